// Round 7
// baseline (509.852 us; speedup 1.0000x reference)
//
#include <hip/hip_runtime.h>
#include <hip/hip_bf16.h>
#include <stdint.h>

#define NTOK 8192
#define DDIM 1024
#define HDIM 4096
#define NEXP 8
#define MAXWL 48

typedef __attribute__((ext_vector_type(4))) float f32x4;
typedef __attribute__((ext_vector_type(8))) short s16x8;
typedef __attribute__((ext_vector_type(8))) unsigned short u16x8;

__device__ __forceinline__ unsigned short f2bf(float f) {
  union { float f; unsigned int u; } v; v.f = f;
  unsigned int u = v.u;
  u += 0x7FFFu + ((u >> 16) & 1u);   // round-to-nearest-even
  return (unsigned short)(u >> 16);
}

typedef __attribute__((address_space(3))) unsigned char lds_u8;
typedef const __attribute__((address_space(1))) unsigned char glb_u8;

__device__ __forceinline__ void load_lds16(const void* g, void* l) {
  __builtin_amdgcn_global_load_lds((glb_u8*)g, (lds_u8*)l, 16, 0, 0);
}

// ---------------- gate + top-1 routing ----------------
__global__ __launch_bounds__(256) void gate_kernel(
    const float* __restrict__ x, const float* __restrict__ Wg,
    const float* __restrict__ bg, int* __restrict__ counts,
    int* __restrict__ lists) {
  const int lane = threadIdx.x & 63;
  const int tok = blockIdx.x * 4 + (threadIdx.x >> 6);
  const float* xr = x + (size_t)tok * DDIM;
  double acc[NEXP];
#pragma unroll
  for (int e = 0; e < NEXP; ++e) acc[e] = 0.0;
#pragma unroll 4
  for (int it = 0; it < DDIM / 64; ++it) {
    const int d = it * 64 + lane;
    const float xv = xr[d];
    const f32x4 w0 = *(const f32x4*)(Wg + (size_t)d * NEXP);
    const f32x4 w1 = *(const f32x4*)(Wg + (size_t)d * NEXP + 4);
#pragma unroll
    for (int j = 0; j < 4; ++j) {
      acc[j]     += (double)xv * (double)w0[j];
      acc[4 + j] += (double)xv * (double)w1[j];
    }
  }
#pragma unroll
  for (int e = 0; e < NEXP; ++e) {
    double v = acc[e];
#pragma unroll
    for (int off = 32; off > 0; off >>= 1) v += __shfl_xor(v, off, 64);
    acc[e] = v;
  }
  if (lane == 0) {
    int best = 0;
    double bv = acc[0] + (double)bg[0];
#pragma unroll
    for (int e = 1; e < NEXP; ++e) {
      const double v = acc[e] + (double)bg[e];
      if (v > bv) { bv = v; best = e; }   // strict > : first max wins (np argmax)
    }
    const int pos = atomicAdd(&counts[best], 1);
    lists[best * NTOK + pos] = tok;
  }
}

// ---- prefix sum + block work-list (BM=256): wl[i]=(e<<20)|bx, nwl in offs[9] ----
__global__ void offs_kernel(const int* __restrict__ counts, int* __restrict__ offs,
                            int* __restrict__ wl) {
  int s = 0;
#pragma unroll
  for (int e = 0; e < NEXP; ++e) { offs[e] = s; s += counts[e]; }
  offs[NEXP] = s;
  int n = 0;
  for (int e = 0; e < NEXP; ++e) {
    const int nb = (counts[e] + 255) >> 8;
    for (int b = 0; b < nb; ++b) wl[n++] = (e << 20) | b;
  }
  offs[NEXP + 1] = n;
}

// -------- gather tokens into expert-sorted order, convert to bf16 --------
__global__ __launch_bounds__(256) void gather_conv_kernel(
    const float* __restrict__ x, const int* __restrict__ offs,
    const int* __restrict__ lists, int* __restrict__ stok,
    unsigned short* __restrict__ xbs) {
  const int p = blockIdx.x * 4 + (threadIdx.x >> 6);   // sorted position
  const int lane = threadIdx.x & 63;
  int e = 0;
#pragma unroll
  for (int k = 1; k < NEXP; ++k) e += (p >= offs[k]) ? 1 : 0;
  const int tok = lists[e * NTOK + (p - offs[e])];
  if (lane == 0) stok[p] = tok;
  const float* src = x + (size_t)tok * DDIM + lane * 16;
  unsigned short* dst = xbs + (size_t)p * DDIM + lane * 16;
#pragma unroll
  for (int q = 0; q < 2; ++q) {
    const f32x4 a = *(const f32x4*)(src + q * 8);
    const f32x4 b = *(const f32x4*)(src + q * 8 + 4);
    u16x8 o;
#pragma unroll
    for (int j = 0; j < 4; ++j) { o[j] = f2bf(a[j]); o[4 + j] = f2bf(b[j]); }
    *(u16x8*)(dst + q * 8) = o;
  }
}

// -- transpose + convert: in [E][R][C] fp32 -> out [E][C][R] bf16; 16B writes --
__global__ __launch_bounds__(256) void transpose_conv_kernel(
    const float* __restrict__ in, unsigned short* __restrict__ out,
    int R, int C) {
  __shared__ unsigned short T[64][66];
  const int e = blockIdx.z;
  const float* ine = in + (size_t)e * R * C;
  unsigned short* oute = out + (size_t)e * C * R;
  const int c0 = blockIdx.x * 64, r0 = blockIdx.y * 64;
  const int t = threadIdx.x;
  const int tr = t >> 4, tc4 = (t & 15) * 4;
#pragma unroll
  for (int p = 0; p < 4; ++p) {
    const int r = tr + p * 16;
    const f32x4 v = *(const f32x4*)(ine + (size_t)(r0 + r) * C + c0 + tc4);
#pragma unroll
    for (int j = 0; j < 4; ++j) T[r][tc4 + j] = f2bf(v[j]);
  }
  __syncthreads();
  const int cc = t >> 3, rr8 = (t & 7) * 8;
#pragma unroll
  for (int p = 0; p < 2; ++p) {
    const int c = cc + p * 32;
    u16x8 o;
#pragma unroll
    for (int j = 0; j < 8; ++j) o[j] = T[rr8 + j][c];
    *(u16x8*)(oute + (size_t)(c0 + c) * R + r0 + rr8) = o;
  }
}

// ---- grouped GEMM, T3-minimum 2-phase recipe (m248 structure), BK=64 ----
// A: bf16 [NTOK][K] expert-sorted rows. Bt: bf16 [E][N][K] (K-contiguous rows).
// Per K-tile: STAGE(next) -> ds_read(cur) -> setprio+MFMA -> vmcnt(0) -> barrier.
// One barrier per tile; stage loads fly under the whole compute cluster.
// Swizzle (round-5-verified, 0 conflicts): LDS row=128B; src 16B-slot
// pre-swizzled by ^(row&7); ds_read slot = ((kk*4+fj) ^ (fr&7)).
template <int BM, int BN, int WM, int WN, int K, int N, bool FUSE1>
__global__ __launch_bounds__(64 * WM * WN, 2) void ffn_kernel(
    const unsigned short* __restrict__ A, const unsigned short* __restrict__ Bt,
    const float* __restrict__ bias, const int* __restrict__ counts,
    const int* __restrict__ offs, const int* __restrict__ wl,
    const int* __restrict__ stok, unsigned short* __restrict__ outb,
    float* __restrict__ outf) {
  constexpr int MF = BM / (WM * 16);
  constexpr int NF = BN / (WN * 16);
  constexpr int ISS_A = BM / 64;     // 512 thr x 16B = 64 rows(128B) per issue
  constexpr int ISS_B = BN / 64;
  constexpr int NT = K / 64;
  constexpr int NCB = N / BN;
  constexpr int NWG = NCB * MAXWL;
  static_assert((NWG & 7) == 0 && (NT & 1) == 0 && NT >= 4, "");

  const int d = blockIdx.x;
  const int logical = (d & 7) * (NWG / 8) + (d >> 3);  // XCD chunking
  const int col0 = (logical / MAXWL) * BN;             // chunk shares B-panel
  const int wli = logical % MAXWL;
  if (wli >= offs[NEXP + 1]) return;
  const int wle = wl[wli];
  const int e = wle >> 20;
  const int bx = wle & 0xFFFFF;
  const int cnt = counts[e];
  const int row0 = offs[e] + bx * BM;

  __shared__ __align__(16) unsigned short As0[BM * 64], Bs0[BN * 64];
  __shared__ __align__(16) unsigned short As1[BM * 64], Bs1[BN * 64];

  const int tid = threadIdx.x;
  const int lane = tid & 63;
  const int w = tid >> 6;
  const int wm = w / WN;
  const int wn = w % WN;
  const int fr = lane & 15;
  const int fj = lane >> 4;

  // staging: thread -> LDS row i*64+(tid>>3), 16B-slot tid&7;
  // global source slot pre-swizzled by ^(row&7)
  const int swz = ((tid & 7) ^ ((tid >> 3) & 7)) * 8;   // ushort offset
  const int rb = tid >> 3;
  const unsigned short* srcA[ISS_A];
#pragma unroll
  for (int i = 0; i < ISS_A; ++i) {
    int gr = row0 + i * 64 + rb;
    if (gr > NTOK - 1) gr = NTOK - 1;   // clamp: garbage rows masked in epilogue
    srcA[i] = A + (size_t)gr * K + swz;
  }
  const unsigned short* Bte = Bt + (size_t)e * N * K;
  const unsigned short* srcB[ISS_B];
#pragma unroll
  for (int i = 0; i < ISS_B; ++i)
    srcB[i] = Bte + (size_t)(col0 + i * 64 + rb) * K + swz;

  f32x4 acc[MF][NF];
#pragma unroll
  for (int m = 0; m < MF; ++m)
#pragma unroll
    for (int n = 0; n < NF; ++n) acc[m][n] = f32x4{0.f, 0.f, 0.f, 0.f};

  auto stage = [&](unsigned short* dA, unsigned short* dB, int k0) {
#pragma unroll
    for (int i = 0; i < ISS_A; ++i)
      load_lds16(srcA[i] + k0, dA + i * 64 * 64 + tid * 8);
#pragma unroll
    for (int i = 0; i < ISS_B; ++i)
      load_lds16(srcB[i] + k0, dB + i * 64 * 64 + tid * 8);
  };

  auto compute = [&](const unsigned short* pA, const unsigned short* pB) {
#pragma unroll
    for (int kk = 0; kk < 2; ++kk) {
      const int js = (((kk << 2) + fj) ^ (fr & 7)) << 3;  // swizzled ushort off
      s16x8 af[MF], bf[NF];
#pragma unroll
      for (int m = 0; m < MF; ++m)
        af[m] = *(const s16x8*)(pA + (wm * MF * 16 + m * 16 + fr) * 64 + js);
#pragma unroll
      for (int n = 0; n < NF; ++n)
        bf[n] = *(const s16x8*)(pB + (wn * NF * 16 + n * 16 + fr) * 64 + js);
      __builtin_amdgcn_s_setprio(1);
#pragma unroll
      for (int m = 0; m < MF; ++m)
#pragma unroll
        for (int n = 0; n < NF; ++n)
          acc[m][n] = __builtin_amdgcn_mfma_f32_16x16x32_bf16(af[m], bf[n],
                                                              acc[m][n], 0, 0, 0);
      __builtin_amdgcn_s_setprio(0);
    }
  };

  // prologue
  stage(As0, Bs0, 0);
  asm volatile("s_waitcnt vmcnt(0)" ::: "memory");
  __builtin_amdgcn_s_barrier();

#pragma unroll 1
  for (int t = 0; t < NT - 2; t += 2) {
    stage(As1, Bs1, (t + 1) * 64);          // issue next under compute
    compute(As0, Bs0);
    asm volatile("s_waitcnt vmcnt(0)" ::: "memory");
    __builtin_amdgcn_s_barrier();
    stage(As0, Bs0, (t + 2) * 64);
    compute(As1, Bs1);
    asm volatile("s_waitcnt vmcnt(0)" ::: "memory");
    __builtin_amdgcn_s_barrier();
  }
  stage(As1, Bs1, (NT - 1) * 64);
  compute(As0, Bs0);
  asm volatile("s_waitcnt vmcnt(0)" ::: "memory");
  __builtin_amdgcn_s_barrier();
  compute(As1, Bs1);

  // epilogue
#pragma unroll
  for (int n = 0; n < NF; ++n) {
    const int col = col0 + wn * NF * 16 + n * 16 + fr;
    const float bv = bias[e * N + col];
#pragma unroll
    for (int m = 0; m < MF; ++m) {
#pragma unroll
      for (int j = 0; j < 4; ++j) {
        const int rl = wm * MF * 16 + m * 16 + fj * 4 + j;
        if (bx * BM + rl < cnt) {
          if constexpr (FUSE1) {
            outb[(size_t)(row0 + rl) * N + col] = f2bf(fmaxf(acc[m][n][j] + bv, 0.f));
          } else {
            outf[(size_t)stok[row0 + rl] * N + col] = acc[m][n][j] + bv;
          }
        }
      }
    }
  }
}

extern "C" void kernel_launch(void* const* d_in, const int* in_sizes, int n_in,
                              void* d_out, int out_size, void* d_ws, size_t ws_size,
                              hipStream_t stream) {
  (void)in_sizes; (void)n_in; (void)out_size;
  const float* x  = (const float*)d_in[0];
  const float* Wg = (const float*)d_in[1];
  const float* bg = (const float*)d_in[2];
  const float* W1 = (const float*)d_in[3];
  const float* b1 = (const float*)d_in[4];
  const float* W2 = (const float*)d_in[5];
  const float* b2 = (const float*)d_in[6];
  float* out = (float*)d_out;

  char* ws = (char*)d_ws;
  const size_t OFF_CNT = 0;                                    // 8 ints
  const size_t OFF_OFF = 128;                                  // offs[0..9]
  const size_t OFF_WL  = 256;                                  // MAXWL ints
  const size_t OFF_LST = 1024;                                 // E*NTOK ints (256 KB)
  const size_t OFF_STK = OFF_LST + (size_t)NEXP * NTOK * 4;    // NTOK ints
  const size_t OFF_XBS = OFF_STK + (size_t)NTOK * 4;           // NTOK*D bf16 (16 MB)
  const size_t OFF_HS  = OFF_XBS + (size_t)NTOK * DDIM * 2;    // NTOK*H bf16 (64 MB)
  const size_t OFF_WT  = OFF_HS + (size_t)NTOK * HDIM * 2;     // E*D*H bf16 (64 MB)
  const size_t NEED    = OFF_WT + (size_t)NEXP * DDIM * HDIM * 2;
  if (ws_size < NEED) return;

  int* counts = (int*)(ws + OFF_CNT);
  int* offs   = (int*)(ws + OFF_OFF);
  int* wl     = (int*)(ws + OFF_WL);
  int* lists  = (int*)(ws + OFF_LST);
  int* stok   = (int*)(ws + OFF_STK);
  unsigned short* xbs = (unsigned short*)(ws + OFF_XBS);
  unsigned short* Hs  = (unsigned short*)(ws + OFF_HS);
  unsigned short* Wt  = (unsigned short*)(ws + OFF_WT);

  hipMemsetAsync(counts, 0, 128, stream);
  gate_kernel<<<NTOK / 4, 256, 0, stream>>>(x, Wg, bg, counts, lists);
  offs_kernel<<<1, 1, 0, stream>>>(counts, offs, wl);
  gather_conv_kernel<<<NTOK / 4, 256, 0, stream>>>(x, offs, lists, stok, xbs);

  // W1 [E][D][H] -> Wt [E][H][D]
  transpose_conv_kernel<<<dim3(HDIM / 64, DDIM / 64, NEXP), 256, 0, stream>>>(
      W1, Wt, DDIM, HDIM);
  // ffn1: Hs[pos] = relu(xbs[pos] @ W1[e] + b1[e]) ; 256x256, 8 waves
  ffn_kernel<256, 256, 2, 4, DDIM, HDIM, true>
      <<<dim3((HDIM / 256) * MAXWL), 512, 0, stream>>>(
          xbs, Wt, b1, counts, offs, wl, stok, Hs, nullptr);
  // W2 [E][H][D] -> Wt [E][D][H]  (reuse buffer after ffn1)
  transpose_conv_kernel<<<dim3(DDIM / 64, HDIM / 64, NEXP), 256, 0, stream>>>(
      W2, Wt, HDIM, DDIM);
  // ffn2: out[stok[pos]] = Hs[pos] @ W2[e] + b2[e] ; 256x128, 8 waves
  ffn_kernel<256, 128, 4, 2, HDIM, DDIM, false>
      <<<dim3((DDIM / 128) * MAXWL), 512, 0, stream>>>(
          Hs, Wt, b2, counts, offs, wl, stok, nullptr, out);
}